// Round 1
// baseline (271.962 us; speedup 1.0000x reference)
//
#include <hip/hip_runtime.h>
#include <hip/hip_bf16.h>

typedef __bf16 bf16x8 __attribute__((ext_vector_type(8)));
typedef float f32x4 __attribute__((ext_vector_type(4)));

#define MFMA(a, b, c) __builtin_amdgcn_mfma_f32_16x16x32_bf16((a), (b), (c), 0, 0, 0)

static constexpr int T_LEN = 2048;
static constexpr int C_DIM = 1024;
static constexpr int H_DIM = 128;
static constexpr int M_ROWS = 8 * 2048;    // 16384
static constexpr int N_COLS = 384;         // 3 * 128

__device__ __forceinline__ ushort f2bf(float f) {
  union { float f; unsigned u; } v; v.f = f;
  unsigned u = v.u;
  u += 0x7fffu + ((u >> 16) & 1u);
  return (ushort)(u >> 16);
}

// ---------------------------------------------------------------------------
// Kernel 0: Wq/Wk/Wv fp32 [1024][128] -> bf16 Wt[384][1024] (transposed)
// ---------------------------------------------------------------------------
__global__ void wt_convert(const float* __restrict__ Wq,
                           const float* __restrict__ Wk,
                           const float* __restrict__ Wv,
                           ushort* __restrict__ wt) {
  int flat = blockIdx.x * 256 + threadIdx.x;   // gc*1024 + c, total 384*1024
  int gc = flat >> 10;
  int c  = flat & 1023;
  int mat = gc >> 7;
  int h   = gc & 127;
  const float* W = (mat == 0) ? Wq : ((mat == 1) ? Wk : Wv);
  wt[flat] = f2bf(W[c * H_DIM + h]);
}

// ---------------------------------------------------------------------------
// Kernel 1: fused QKV projection.  X[16384][1024] fp32 @ Wt^T -> q,k bf16
// [16384][128]; v stored transposed vt[8][128][2048] bf16.
// Block: 256 thr (4 waves). Tile: 64 rows x 384 cols. K-step 32.
// ---------------------------------------------------------------------------
#define LDA 40   // padded LDS row stride (bf16 elems) -> 2-way max conflicts

__global__ __launch_bounds__(256) void qkv_gemm(const float* __restrict__ X,
                                                const ushort* __restrict__ wt,
                                                ushort* __restrict__ qws,
                                                ushort* __restrict__ kws,
                                                ushort* __restrict__ vtws) {
  __shared__ ushort As[64 * LDA];
  const int tid = threadIdx.x;
  const int wid = tid >> 6, lane = tid & 63;
  const int lg = lane >> 4, lr = lane & 15;
  const int m0 = blockIdx.x * 64;

  f32x4 acc[4][6];
#pragma unroll
  for (int r = 0; r < 4; ++r)
#pragma unroll
    for (int c = 0; c < 6; ++c)
      acc[r][c] = f32x4{0.f, 0.f, 0.f, 0.f};

  for (int kt = 0; kt < 32; ++kt) {
    // stage A tile: 64 rows x 32 k, fp32 -> bf16 into LDS
#pragma unroll
    for (int i = 0; i < 2; ++i) {
      int idx = tid + i * 256;          // 0..511
      int row = idx >> 3, c4 = idx & 7;
      float4 v = *(const float4*)&X[(size_t)(m0 + row) * C_DIM + kt * 32 + c4 * 4];
      ushort4 bv;
      bv.x = f2bf(v.x); bv.y = f2bf(v.y); bv.z = f2bf(v.z); bv.w = f2bf(v.w);
      *(ushort4*)&As[row * LDA + c4 * 4] = bv;
    }
    __syncthreads();

    bf16x8 a[4];
#pragma unroll
    for (int r = 0; r < 4; ++r)
      a[r] = *(const bf16x8*)&As[(r * 16 + lr) * LDA + lg * 8];

#pragma unroll
    for (int c = 0; c < 6; ++c) {
      int gc = wid * 96 + c * 16 + lr;
      bf16x8 bfrag = *(const bf16x8*)&wt[(size_t)gc * C_DIM + kt * 32 + lg * 8];
#pragma unroll
      for (int r = 0; r < 4; ++r)
        acc[r][c] = MFMA(a[r], bfrag, acc[r][c]);
    }
    __syncthreads();
  }

  // epilogue: C frag layout col=lane&15, row=(lane>>4)*4+j
#pragma unroll
  for (int c = 0; c < 6; ++c) {
    int gc = wid * 96 + c * 16 + lr;     // 16-aligned range: mat uniform per frag
    int mat = gc >> 7, h = gc & 127;
#pragma unroll
    for (int r = 0; r < 4; ++r) {
#pragma unroll
      for (int j = 0; j < 4; ++j) {
        int gr = m0 + r * 16 + lg * 4 + j;
        ushort ov = f2bf(acc[r][c][j]);
        if (mat == 0) {
          qws[(size_t)gr * H_DIM + h] = ov;
        } else if (mat == 1) {
          kws[(size_t)gr * H_DIM + h] = ov;
        } else {
          int b = gr >> 11, t = gr & 2047;
          vtws[((size_t)b * H_DIM + h) * T_LEN + t] = ov;
        }
      }
    }
  }
}

// ---------------------------------------------------------------------------
// Kernel 2: causal flash attention.
// grid (32 qtiles, 8 batches), 256 thr (4 waves), wave owns 16 q rows.
// K/V read straight from global (L2-resident per batch).
// ---------------------------------------------------------------------------
__global__ __launch_bounds__(256) void attn_fwd(const ushort* __restrict__ qws,
                                                const ushort* __restrict__ kws,
                                                const ushort* __restrict__ vtws,
                                                float* __restrict__ out) {
  __shared__ ushort Pl[4][16][72];   // per-wave P tile, padded stride 72
  const int tid = threadIdx.x;
  const int wid = tid >> 6, lane = tid & 63;
  const int lg = lane >> 4, lr = lane & 15;
  const int qt = blockIdx.x;
  const int b  = blockIdx.y;
  const int q0 = qt * 64 + wid * 16;
  const size_t tokbase = (size_t)b * T_LEN;

  // hoist Q fragments (A operand: row=lane&15, k=(lane>>4)*8+j)
  bf16x8 qf[4];
#pragma unroll
  for (int hk = 0; hk < 4; ++hk)
    qf[hk] = *(const bf16x8*)&qws[(tokbase + q0 + lr) * H_DIM + hk * 32 + lg * 8];

  f32x4 acc[8];
#pragma unroll
  for (int hf = 0; hf < 8; ++hf) acc[hf] = f32x4{0.f, 0.f, 0.f, 0.f};
  float mrun[4], lrun[4];
#pragma unroll
  for (int j = 0; j < 4; ++j) { mrun[j] = -INFINITY; lrun[j] = 0.f; }

  const float SCL = 0.03125f * 1.44269504f;   // C^-0.5 folded with log2(e)

  for (int kvt = 0; kvt <= qt; ++kvt) {
    const int kv0 = kvt * 64;

    // S = Q K^T  (per wave: 16 q rows x 64 kv)
    f32x4 s[4];
#pragma unroll
    for (int c = 0; c < 4; ++c) {
      f32x4 sc = f32x4{0.f, 0.f, 0.f, 0.f};
#pragma unroll
      for (int hk = 0; hk < 4; ++hk) {
        bf16x8 kf = *(const bf16x8*)&kws[(tokbase + kv0 + c * 16 + lr) * H_DIM + hk * 32 + lg * 8];
        sc = MFMA(qf[hk], kf, sc);
      }
      s[c] = sc;
    }

    // scale into log2 domain + causal mask (only diagonal tile needs mask)
    if (kvt == qt) {
#pragma unroll
      for (int c = 0; c < 4; ++c)
#pragma unroll
        for (int j = 0; j < 4; ++j) {
          int kv = kv0 + c * 16 + lr;
          int qr = q0 + lg * 4 + j;
          s[c][j] = (kv <= qr) ? s[c][j] * SCL : -INFINITY;
        }
    } else {
#pragma unroll
      for (int c = 0; c < 4; ++c)
#pragma unroll
        for (int j = 0; j < 4; ++j) s[c][j] *= SCL;
    }

    // row max across the 16-lane kv groups
    float mx[4];
#pragma unroll
    for (int j = 0; j < 4; ++j)
      mx[j] = fmaxf(fmaxf(s[0][j], s[1][j]), fmaxf(s[2][j], s[3][j]));
#pragma unroll
    for (int off = 8; off >= 1; off >>= 1)
#pragma unroll
      for (int j = 0; j < 4; ++j)
        mx[j] = fmaxf(mx[j], __shfl_xor(mx[j], off));

    float mnew[4], scold[4];
#pragma unroll
    for (int j = 0; j < 4; ++j) {
      mnew[j] = fmaxf(mrun[j], mx[j]);
      scold[j] = exp2f(mrun[j] - mnew[j]);
    }

    // P = exp2(s - m), write bf16 P to LDS (C-layout -> A-layout round trip)
    float rsum[4] = {0.f, 0.f, 0.f, 0.f};
#pragma unroll
    for (int c = 0; c < 4; ++c)
#pragma unroll
      for (int j = 0; j < 4; ++j) {
        float p = exp2f(s[c][j] - mnew[j]);
        rsum[j] += p;
        Pl[wid][lg * 4 + j][c * 16 + lr] = f2bf(p);
      }
#pragma unroll
    for (int off = 8; off >= 1; off >>= 1)
#pragma unroll
      for (int j = 0; j < 4; ++j) rsum[j] += __shfl_xor(rsum[j], off);

#pragma unroll
    for (int j = 0; j < 4; ++j) {
      lrun[j] = lrun[j] * scold[j] + rsum[j];
      mrun[j] = mnew[j];
    }
#pragma unroll
    for (int hf = 0; hf < 8; ++hf)
#pragma unroll
      for (int j = 0; j < 4; ++j) acc[hf][j] *= scold[j];

    // read P as A fragments (within-wave LDS, no barrier needed)
    bf16x8 pa[2];
#pragma unroll
    for (int f = 0; f < 2; ++f)
      pa[f] = *(const bf16x8*)&Pl[wid][lr][f * 32 + lg * 8];

    // O += P V   (B operand from transposed V: contiguous along kv)
    const ushort* vb = vtws + (size_t)b * H_DIM * T_LEN;
#pragma unroll
    for (int hf = 0; hf < 8; ++hf) {
#pragma unroll
      for (int f = 0; f < 2; ++f) {
        bf16x8 vf = *(const bf16x8*)&vb[(size_t)(hf * 16 + lr) * T_LEN + kv0 + f * 32 + lg * 8];
        acc[hf] = MFMA(pa[f], vf, acc[hf]);
      }
    }
  }

  // epilogue: out fp32 [b][q][h]
#pragma unroll
  for (int j = 0; j < 4; ++j) {
    float inv = 1.0f / lrun[j];
    size_t row = (tokbase + q0 + lg * 4 + j) * H_DIM;
#pragma unroll
    for (int hf = 0; hf < 8; ++hf)
      out[row + hf * 16 + lr] = acc[hf][j] * inv;
  }
}

// ---------------------------------------------------------------------------
extern "C" void kernel_launch(void* const* d_in, const int* in_sizes, int n_in,
                              void* d_out, int out_size, void* d_ws, size_t ws_size,
                              hipStream_t stream) {
  const float* emb = (const float*)d_in[0];
  const float* Wq  = (const float*)d_in[1];
  const float* Wk  = (const float*)d_in[2];
  const float* Wv  = (const float*)d_in[3];
  float* out = (float*)d_out;

  ushort* wt   = (ushort*)d_ws;                       // [384][1024] bf16
  ushort* qws  = wt  + (size_t)N_COLS * C_DIM;        // [16384][128] bf16
  ushort* kws  = qws + (size_t)M_ROWS * H_DIM;        // [16384][128] bf16
  ushort* vtws = kws + (size_t)M_ROWS * H_DIM;        // [8][128][2048] bf16

  wt_convert<<<(N_COLS * C_DIM) / 256, 256, 0, stream>>>(Wq, Wk, Wv, wt);
  qkv_gemm<<<M_ROWS / 64, 256, 0, stream>>>(emb, wt, qws, kws, vtws);
  attn_fwd<<<dim3(T_LEN / 64, 8), 256, 0, stream>>>(qws, kws, vtws, out);
}

// Round 2
// 159.923 us; speedup vs baseline: 1.7006x; 1.7006x over previous
//
#include <hip/hip_runtime.h>
#include <hip/hip_bf16.h>

typedef __bf16 bf16x8 __attribute__((ext_vector_type(8)));
typedef float f32x4 __attribute__((ext_vector_type(4)));

#define MFMA(a, b, c) __builtin_amdgcn_mfma_f32_16x16x32_bf16((a), (b), (c), 0, 0, 0)

static constexpr int T_LEN = 2048;
static constexpr int C_DIM = 1024;
static constexpr int H_DIM = 128;
static constexpr int M_ROWS = 8 * 2048;    // 16384
static constexpr int N_COLS = 384;         // 3 * 128

__device__ __forceinline__ ushort f2bf(float f) {
  union { float f; unsigned u; } v; v.f = f;
  unsigned u = v.u;
  u += 0x7fffu + ((u >> 16) & 1u);
  return (ushort)(u >> 16);
}

// ---------------------------------------------------------------------------
// Kernel 0: Wq/Wk/Wv fp32 [1024][128] -> bf16 Wt[384][1024] (transposed)
// ---------------------------------------------------------------------------
__global__ void wt_convert(const float* __restrict__ Wq,
                           const float* __restrict__ Wk,
                           const float* __restrict__ Wv,
                           ushort* __restrict__ wt) {
  int flat = blockIdx.x * 256 + threadIdx.x;   // gc*1024 + c, total 384*1024
  int gc = flat >> 10;
  int c  = flat & 1023;
  int mat = gc >> 7;
  int h   = gc & 127;
  const float* W = (mat == 0) ? Wq : ((mat == 1) ? Wk : Wv);
  wt[flat] = f2bf(W[c * H_DIM + h]);
}

// ---------------------------------------------------------------------------
// Kernel 1: fused QKV projection.  X[16384][1024] fp32 @ Wt^T -> q,k bf16
// [16384][128]; v stored transposed vt[8][128][2048] bf16.
// Block: 256 thr (4 waves). Tile: 32 rows x 384 cols -> 512 blocks (2/CU).
// ---------------------------------------------------------------------------
#define LDA 40   // padded LDS row stride (bf16 elems)

__global__ __launch_bounds__(256, 4) void qkv_gemm(const float* __restrict__ X,
                                                   const ushort* __restrict__ wt,
                                                   ushort* __restrict__ qws,
                                                   ushort* __restrict__ kws,
                                                   ushort* __restrict__ vtws) {
  __shared__ ushort As[32 * LDA];
  const int tid = threadIdx.x;
  const int wid = tid >> 6, lane = tid & 63;
  const int lg = lane >> 4, lr = lane & 15;
  const int m0 = blockIdx.x * 32;

  f32x4 acc[2][6];
#pragma unroll
  for (int r = 0; r < 2; ++r)
#pragma unroll
    for (int c = 0; c < 6; ++c)
      acc[r][c] = f32x4{0.f, 0.f, 0.f, 0.f};

  const int srow = tid >> 3, sc4 = tid & 7;

  for (int kt = 0; kt < 32; ++kt) {
    // stage A tile: 32 rows x 32 k, fp32 -> bf16 into LDS (1 float4/thread)
    float4 v = *(const float4*)&X[(size_t)(m0 + srow) * C_DIM + kt * 32 + sc4 * 4];
    ushort4 bv;
    bv.x = f2bf(v.x); bv.y = f2bf(v.y); bv.z = f2bf(v.z); bv.w = f2bf(v.w);
    __syncthreads();
    *(ushort4*)&As[srow * LDA + sc4 * 4] = bv;
    __syncthreads();

    bf16x8 a[2];
#pragma unroll
    for (int r = 0; r < 2; ++r)
      a[r] = *(const bf16x8*)&As[(r * 16 + lr) * LDA + lg * 8];

#pragma unroll
    for (int c = 0; c < 6; ++c) {
      int gc = wid * 96 + c * 16 + lr;
      bf16x8 bfrag = *(const bf16x8*)&wt[(size_t)gc * C_DIM + kt * 32 + lg * 8];
#pragma unroll
      for (int r = 0; r < 2; ++r)
        acc[r][c] = MFMA(a[r], bfrag, acc[r][c]);
    }
  }

  // epilogue: C frag layout col=lane&15, row=(lane>>4)*4+j
#pragma unroll
  for (int c = 0; c < 6; ++c) {
    int gc = wid * 96 + c * 16 + lr;     // 16-aligned range: mat uniform per frag
    int mat = gc >> 7, h = gc & 127;
#pragma unroll
    for (int r = 0; r < 2; ++r) {
#pragma unroll
      for (int j = 0; j < 4; ++j) {
        int gr = m0 + r * 16 + lg * 4 + j;
        ushort ov = f2bf(acc[r][c][j]);
        if (mat == 0) {
          qws[(size_t)gr * H_DIM + h] = ov;
        } else if (mat == 1) {
          kws[(size_t)gr * H_DIM + h] = ov;
        } else {
          int b = gr >> 11, t = gr & 2047;
          vtws[((size_t)b * H_DIM + h) * T_LEN + t] = ov;
        }
      }
    }
  }
}

// ---------------------------------------------------------------------------
// Kernel 2: causal flash attention, split-KV across the block's 4 waves.
// 1024 blocks (b = bid&7 pins batch to one XCD), 256 thr.
// Block owns 16 q rows; wave w does kv tiles w, w+4, ... with its own
// online-softmax state; merge through LDS at the end.
// ---------------------------------------------------------------------------
__global__ __launch_bounds__(256, 4) void attn_fwd(const ushort* __restrict__ qws,
                                                   const ushort* __restrict__ kws,
                                                   const ushort* __restrict__ vtws,
                                                   float* __restrict__ out) {
  __shared__ ushort Pl[4][16][72];     // per-wave P tile, padded stride 72
  __shared__ float Macc[16][128];      // merge accumulator
  __shared__ float Sm[4][16], Sl[4][16];

  const int tid = threadIdx.x;
  const int wid = tid >> 6, lane = tid & 63;
  const int lg = lane >> 4, lr = lane & 15;
  const int bid = blockIdx.x;
  const int b  = bid & 7;              // wgid%8 -> XCD: per-batch K/V stays in one L2
  const int qi = bid >> 3;             // 0..127
  const int q0 = qi * 16;
  const int nt = (qi >> 2) + 1;        // causal 64-kv tiles for this q tile
  const size_t tokbase = (size_t)b * T_LEN;

  // hoist Q fragments (A operand: row=lane&15, k=(lane>>4)*8+j) — same rows all waves
  bf16x8 qf[4];
#pragma unroll
  for (int hk = 0; hk < 4; ++hk)
    qf[hk] = *(const bf16x8*)&qws[(tokbase + q0 + lr) * H_DIM + hk * 32 + lg * 8];

  f32x4 acc[8];
#pragma unroll
  for (int hf = 0; hf < 8; ++hf) acc[hf] = f32x4{0.f, 0.f, 0.f, 0.f};
  float mrun[4], lrun[4];
#pragma unroll
  for (int j = 0; j < 4; ++j) { mrun[j] = -INFINITY; lrun[j] = 0.f; }

  const float SCL = 0.03125f * 1.44269504f;   // C^-0.5 folded with log2(e)
  const ushort* vb = vtws + (size_t)b * H_DIM * T_LEN;

  for (int kvt = wid; kvt < nt; kvt += 4) {
    const int kv0 = kvt * 64;

    // S = Q K^T  (16 q rows x 64 kv)
    f32x4 s[4];
#pragma unroll
    for (int c = 0; c < 4; ++c) {
      f32x4 sc = f32x4{0.f, 0.f, 0.f, 0.f};
#pragma unroll
      for (int hk = 0; hk < 4; ++hk) {
        bf16x8 kf = *(const bf16x8*)&kws[(tokbase + kv0 + c * 16 + lr) * H_DIM + hk * 32 + lg * 8];
        sc = MFMA(qf[hk], kf, sc);
      }
      s[c] = sc;
    }

    // scale into log2 domain + causal mask (diagonal tile only)
    if (kvt == nt - 1) {
#pragma unroll
      for (int c = 0; c < 4; ++c)
#pragma unroll
        for (int j = 0; j < 4; ++j) {
          int kv = kv0 + c * 16 + lr;
          int qr = q0 + lg * 4 + j;
          s[c][j] = (kv <= qr) ? s[c][j] * SCL : -INFINITY;
        }
    } else {
#pragma unroll
      for (int c = 0; c < 4; ++c)
#pragma unroll
        for (int j = 0; j < 4; ++j) s[c][j] *= SCL;
    }

    // row max across the 16-lane kv groups
    float mx[4];
#pragma unroll
    for (int j = 0; j < 4; ++j)
      mx[j] = fmaxf(fmaxf(s[0][j], s[1][j]), fmaxf(s[2][j], s[3][j]));
#pragma unroll
    for (int off = 8; off >= 1; off >>= 1)
#pragma unroll
      for (int j = 0; j < 4; ++j)
        mx[j] = fmaxf(mx[j], __shfl_xor(mx[j], off));

    float mnew[4], scold[4];
#pragma unroll
    for (int j = 0; j < 4; ++j) {
      mnew[j] = fmaxf(mrun[j], mx[j]);
      scold[j] = exp2f(mrun[j] - mnew[j]);
    }

    // P = exp2(s - m), bf16 P to per-wave LDS (C-layout -> A-layout)
    float rsum[4] = {0.f, 0.f, 0.f, 0.f};
#pragma unroll
    for (int c = 0; c < 4; ++c)
#pragma unroll
      for (int j = 0; j < 4; ++j) {
        float p = exp2f(s[c][j] - mnew[j]);
        rsum[j] += p;
        Pl[wid][lg * 4 + j][c * 16 + lr] = f2bf(p);
      }
#pragma unroll
    for (int off = 8; off >= 1; off >>= 1)
#pragma unroll
      for (int j = 0; j < 4; ++j) rsum[j] += __shfl_xor(rsum[j], off);

#pragma unroll
    for (int j = 0; j < 4; ++j) {
      lrun[j] = lrun[j] * scold[j] + rsum[j];
      mrun[j] = mnew[j];
    }
#pragma unroll
    for (int hf = 0; hf < 8; ++hf)
#pragma unroll
      for (int j = 0; j < 4; ++j) acc[hf][j] *= scold[j];

    // read P as A fragments (within-wave LDS, no barrier needed)
    bf16x8 pa[2];
#pragma unroll
    for (int f = 0; f < 2; ++f)
      pa[f] = *(const bf16x8*)&Pl[wid][lr][f * 32 + lg * 8];

    // O += P V   (B operand from transposed V: contiguous along kv)
#pragma unroll
    for (int hf = 0; hf < 8; ++hf) {
#pragma unroll
      for (int f = 0; f < 2; ++f) {
        bf16x8 vf = *(const bf16x8*)&vb[(size_t)(hf * 16 + lr) * T_LEN + kv0 + f * 32 + lg * 8];
        acc[hf] = MFMA(pa[f], vf, acc[hf]);
      }
    }
  }

  // ---- merge the 4 waves' partial (m, l, acc) ----
  if (lr == 0) {
#pragma unroll
    for (int j = 0; j < 4; ++j) {
      Sm[wid][lg * 4 + j] = mrun[j];
      Sl[wid][lg * 4 + j] = lrun[j];
    }
  }
  __syncthreads();

  float inv_l[4];
#pragma unroll
  for (int j = 0; j < 4; ++j) {
    int r = lg * 4 + j;
    float mg = fmaxf(fmaxf(Sm[0][r], Sm[1][r]), fmaxf(Sm[2][r], Sm[3][r]));
    float lt = Sl[0][r] * exp2f(Sm[0][r] - mg) + Sl[1][r] * exp2f(Sm[1][r] - mg)
             + Sl[2][r] * exp2f(Sm[2][r] - mg) + Sl[3][r] * exp2f(Sm[3][r] - mg);
    float sc = exp2f(mrun[j] - mg);       // -inf -> 0 for waves with no tiles
#pragma unroll
    for (int hf = 0; hf < 8; ++hf) acc[hf][j] *= sc;
    inv_l[j] = 1.0f / lt;
  }

  if (wid == 1) {
#pragma unroll
    for (int hf = 0; hf < 8; ++hf)
#pragma unroll
      for (int j = 0; j < 4; ++j)
        Macc[lg * 4 + j][hf * 16 + lr] = acc[hf][j];
  }
  __syncthreads();
  if (wid == 2) {
#pragma unroll
    for (int hf = 0; hf < 8; ++hf)
#pragma unroll
      for (int j = 0; j < 4; ++j)
        Macc[lg * 4 + j][hf * 16 + lr] += acc[hf][j];
  }
  __syncthreads();
  if (wid == 3) {
#pragma unroll
    for (int hf = 0; hf < 8; ++hf)
#pragma unroll
      for (int j = 0; j < 4; ++j)
        Macc[lg * 4 + j][hf * 16 + lr] += acc[hf][j];
  }
  __syncthreads();
  if (wid == 0) {
#pragma unroll
    for (int j = 0; j < 4; ++j) {
      size_t row = (tokbase + q0 + lg * 4 + j) * H_DIM;
#pragma unroll
      for (int hf = 0; hf < 8; ++hf)
        out[row + hf * 16 + lr] =
            (acc[hf][j] + Macc[lg * 4 + j][hf * 16 + lr]) * inv_l[j];
    }
  }
}

// ---------------------------------------------------------------------------
extern "C" void kernel_launch(void* const* d_in, const int* in_sizes, int n_in,
                              void* d_out, int out_size, void* d_ws, size_t ws_size,
                              hipStream_t stream) {
  const float* emb = (const float*)d_in[0];
  const float* Wq  = (const float*)d_in[1];
  const float* Wk  = (const float*)d_in[2];
  const float* Wv  = (const float*)d_in[3];
  float* out = (float*)d_out;

  ushort* wt   = (ushort*)d_ws;                       // [384][1024] bf16
  ushort* qws  = wt  + (size_t)N_COLS * C_DIM;        // [16384][128] bf16
  ushort* kws  = qws + (size_t)M_ROWS * H_DIM;        // [16384][128] bf16
  ushort* vtws = kws + (size_t)M_ROWS * H_DIM;        // [8][128][2048] bf16

  wt_convert<<<(N_COLS * C_DIM) / 256, 256, 0, stream>>>(Wq, Wk, Wv, wt);
  qkv_gemm<<<M_ROWS / 32, 256, 0, stream>>>(emb, wt, qws, kws, vtws);
  attn_fwd<<<dim3(T_LEN / 16 * 8), 256, 0, stream>>>(qws, kws, vtws, out);
}